// Round 8
// baseline (43.822 us; speedup 1.0000x reference)
//
#include <hip/hip_runtime.h>
#include <hip/hip_bf16.h>
#include <math.h>

#define B_ 128
#define IN_ 1024
#define D_ 128
#define H_ 512
#define S_ 256

typedef __attribute__((ext_vector_type(8))) short short8v;
typedef __attribute__((ext_vector_type(8))) unsigned short ushort8v;
typedef __attribute__((ext_vector_type(4))) unsigned short ushort4v;
typedef __attribute__((ext_vector_type(4))) float f32x4;

__device__ __forceinline__ float softplusf(float x) {
  return fmaxf(x, 0.f) + log1pf(expf(-fabsf(x)));
}

__device__ __forceinline__ unsigned short f2bf(float f) {
  unsigned u = __float_as_uint(f);
  unsigned r = (u + 0x7fff + ((u >> 16) & 1)) >> 16;   // RNE
  return (unsigned short)r;
}

// ============ fused prep kernel ============
// [0,64)    : pack W1 w-half -> bf16 MFMA-fragment order Bp   (verified)
// [64,192)  : log_pwx partial logits — 8-b-shared W sweep     (W read 16x not 128x)
// [192,448) : log_pxw partials — 4-b-shared, zw-shaped        (W read 2x not 8x)
// [448,704) : zb1 + f_zw partials                             (verified)
__global__ __launch_bounds__(256) void Kprep(
    const float* __restrict__ x, const float* __restrict__ w,
    const float* __restrict__ z, const float* __restrict__ W,
    const float* __restrict__ cvec, const float* __restrict__ W1,
    const float* __restrict__ b1, const float* __restrict__ W2,
    unsigned short* __restrict__ Bp, float* __restrict__ l2part,
    float* __restrict__ pxw_part, float* __restrict__ zb1,
    float* __restrict__ fzw_part) {
  __shared__ float smem[1024];
  const int blk = blockIdx.x;
  const int t = threadIdx.x;

  if (blk < 64) {
    // ---- pack Bp (verified): frag=hblk*4+ks, h=hblk*16+(l&15), k=ks*32+(l>>4)*8+j
    const int o = (blk * 256 + t) * 4;
    const int frag = o >> 9;
    const int l = (o >> 3) & 63;
    const int j0 = o & 7;
    const int h = (frag >> 2) * 16 + (l & 15);
    const int k0 = (frag & 3) * 32 + ((l >> 4) << 3) + j0;
    const float4 v = *(const float4*)(W1 + (size_t)h * 256 + 128 + k0);
    ushort4v u;
    u[0] = f2bf(v.x); u[1] = f2bf(v.y); u[2] = f2bf(v.z); u[3] = f2bf(v.w);
    *(ushort4v*)(Bp + o) = u;
  } else if (blk < 192) {
    // ---- pwx partial: block = (bg of 8 b's, kc of 8 i-chunks of 128)
    const int bb0 = blk - 64;
    const int bg = bb0 >> 3, kc = bb0 & 7;   // bg 0..15, kc 0..7
    float* xs = smem;                        // [8][128]
    for (int e = t; e < 1024; e += 256) {
      const int bb = e >> 7, i = e & 127;
      xs[e] = x[(size_t)(bg * 8 + bb) * IN_ + kc * 128 + i];
    }
    __syncthreads();
    const int d = t & 127, half = t >> 7;    // half -> 4-b subrange
    float acc0 = 0.f, acc1 = 0.f, acc2 = 0.f, acc3 = 0.f;
    const float* __restrict__ Wp = W + (size_t)(kc * 128) * D_ + d;
    #pragma unroll 4
    for (int i = 0; i < 128; ++i) {
      const float wv = Wp[(size_t)i * D_];
      acc0 = fmaf(wv, xs[(half * 4 + 0) * 128 + i], acc0);
      acc1 = fmaf(wv, xs[(half * 4 + 1) * 128 + i], acc1);
      acc2 = fmaf(wv, xs[(half * 4 + 2) * 128 + i], acc2);
      acc3 = fmaf(wv, xs[(half * 4 + 3) * 128 + i], acc3);
    }
    const int bbase = bg * 8 + half * 4;
    l2part[((size_t)(bbase + 0) * 8 + kc) * 128 + d] = acc0;
    l2part[((size_t)(bbase + 1) * 8 + kc) * 128 + d] = acc1;
    l2part[((size_t)(bbase + 2) * 8 + kc) * 128 + d] = acc2;
    l2part[((size_t)(bbase + 3) * 8 + kc) * 128 + d] = acc3;
  } else if (blk < 448) {
    // ---- pxw partial: block = (b-quad, ic of 8), wave = b, 16 lanes/row
    const int bb0 = blk - 192;
    const int bq = bb0 >> 3, ic = bb0 & 7;   // bq 0..31, ic 0..7
    float* ws_ = smem;                       // [4][128]
    for (int e = t; e < 512; e += 256) ws_[e] = w[bq * 512 + e];
    __syncthreads();
    const int bs = t >> 6, lane = t & 63;
    const int c16 = lane & 15, rsub = lane >> 4;
    const int b = bq * 4 + bs;
    float wreg[8];
    #pragma unroll
    for (int j = 0; j < 8; ++j) wreg[j] = ws_[bs * 128 + c16 * 8 + j];
    float term = 0.f;
    #pragma unroll 2
    for (int it = 0; it < 32; ++it) {
      const int i = ic * 128 + it * 4 + rsub;
      const float4* __restrict__ rp = (const float4*)(W + (size_t)i * D_ + c16 * 8);
      const float4 va = rp[0], vb = rp[1];
      float dot = 0.f;
      dot = fmaf(va.x, wreg[0], dot); dot = fmaf(va.y, wreg[1], dot);
      dot = fmaf(va.z, wreg[2], dot); dot = fmaf(va.w, wreg[3], dot);
      dot = fmaf(vb.x, wreg[4], dot); dot = fmaf(vb.y, wreg[5], dot);
      dot = fmaf(vb.z, wreg[6], dot); dot = fmaf(vb.w, wreg[7], dot);
      dot += __shfl_xor(dot, 1); dot += __shfl_xor(dot, 2);
      dot += __shfl_xor(dot, 4); dot += __shfl_xor(dot, 8);
      if (c16 == 0) {
        const float lg = dot + cvec[i];
        term += x[(size_t)b * IN_ + i] * lg - softplusf(lg);
      }
    }
    term += __shfl_xor(term, 16);
    term += __shfl_xor(term, 32);
    if (lane == 0) pxw_part[b * 8 + ic] = term;
  } else {
    // ---- zw (verified): (b-quad, hc of 8), wave = b, 16 lanes per h-row
    const int bb = blk - 448;
    const int bq = bb >> 3, hc = bb & 7;
    float* zs  = smem;           // 512
    float* ws2 = smem + 512;     // 512
    for (int e = t; e < 512; e += 256) {
      zs[e]  = z[bq * 512 + e];
      ws2[e] = w[bq * 512 + e];
    }
    __syncthreads();
    const int bs = t >> 6, lane = t & 63;
    const int c16 = lane & 15, rsub = lane >> 4;
    const int b = bq * 4 + bs;
    float zreg[16];
    #pragma unroll
    for (int j = 0; j < 16; ++j)
      zreg[j] = (c16 < 8) ? zs[bs * 128 + c16 * 16 + j]
                          : ws2[bs * 128 + c16 * 16 - 128 + j];
    float fpacc = 0.f;
    #pragma unroll 2
    for (int it = 0; it < 16; ++it) {
      const int h = hc * 64 + it * 4 + rsub;
      const float4* __restrict__ rp = (const float4*)(W1 + (size_t)h * 256 + c16 * 16);
      float dot = 0.f;
      #pragma unroll
      for (int q = 0; q < 4; ++q) {
        const float4 v = rp[q];
        dot = fmaf(v.x, zreg[4 * q + 0], dot);
        dot = fmaf(v.y, zreg[4 * q + 1], dot);
        dot = fmaf(v.z, zreg[4 * q + 2], dot);
        dot = fmaf(v.w, zreg[4 * q + 3], dot);
      }
      dot += __shfl_xor(dot, 1); dot += __shfl_xor(dot, 2);
      dot += __shfl_xor(dot, 4);
      const float other = __shfl_xor(dot, 8);
      if (c16 == 0) {
        const float zp = dot + b1[h];
        zb1[(size_t)b * H_ + h] = zp;
        fpacc += fmaxf(zp + other, 0.f) * W2[h];
      }
    }
    fpacc += __shfl_xor(fpacc, 16);
    fpacc += __shfl_xor(fpacc, 32);
    if (lane == 0) fzw_part[b * 8 + hc] = fpacc;
  }
}

// ============ MFMA GEMM (verified): 512 blocks x 256 thr, block = (b, s-quarter) ============
__global__ __launch_bounds__(256) void Kmfma(
    const float* __restrict__ wt, const unsigned short* __restrict__ Bp,
    const float* __restrict__ zb1, const float* __restrict__ W2,
    const float* __restrict__ b2, float* __restrict__ mpart,
    float* __restrict__ lpart) {
  const int blk = blockIdx.x;            // 512 = sq*128 + b
  const int b = blk & (B_ - 1);
  const int sq = blk >> 7;               // 0..3
  const int s0 = sq * 64;
  const int t = threadIdx.x;
  const int lane = t & 63, wv = t >> 6;  // 4 waves

  __shared__ unsigned short atile[64 * 128];   // 16 KB, XOR-swizzled bf16
  __shared__ float zb1s[H_];
  __shared__ float w2s[H_];
  __shared__ float red[4][64];

  zb1s[t] = zb1[(size_t)b * H_ + t];
  zb1s[256 + t] = zb1[(size_t)b * H_ + 256 + t];
  w2s[t] = W2[t];
  w2s[256 + t] = W2[256 + t];

  // stage A: 64 rows x 128 d, fp32 -> bf16, granule swizzle g ^= r&15 (verified)
  {
    const int r = t >> 2;                // 0..63
    const int g0 = (t & 3) * 4;
    const float* __restrict__ src = wt + ((size_t)(s0 + r) * B_ + b) * D_;
    #pragma unroll
    for (int gg = 0; gg < 4; ++gg) {
      const int g = g0 + gg;
      const float4 v0 = *(const float4*)(src + g * 8);
      const float4 v1 = *(const float4*)(src + g * 8 + 4);
      ushort8v u;
      u[0] = f2bf(v0.x); u[1] = f2bf(v0.y); u[2] = f2bf(v0.z); u[3] = f2bf(v0.w);
      u[4] = f2bf(v1.x); u[5] = f2bf(v1.y); u[6] = f2bf(v1.z); u[7] = f2bf(v1.w);
      *(ushort8v*)&atile[r * 128 + ((g ^ (r & 15)) << 3)] = u;
    }
  }
  __syncthreads();

  // A fragments (verified): row = m*16 + (lane&15), k = ks*32 + (lane>>4)*8 + j
  short8v afr[4][4];
  #pragma unroll
  for (int m = 0; m < 4; ++m) {
    const int arow = m * 16 + (lane & 15);
    #pragma unroll
    for (int ks = 0; ks < 4; ++ks) {
      const int g = ks * 4 + (lane >> 4);
      afr[m][ks] = *(const short8v*)&atile[arow * 128 + ((g ^ (arow & 15)) << 3)];
    }
  }

  float fsum[4][4];
  #pragma unroll
  for (int m = 0; m < 4; ++m)
    #pragma unroll
    for (int j = 0; j < 4; ++j) fsum[m][j] = 0.f;

  const int hl = lane & 15;
  #pragma unroll 2
  for (int nt = 0; nt < 8; ++nt) {
    const int hblk = wv * 8 + nt;        // 0..31
    const int hrow = hblk * 16 + hl;
    f32x4 acc0 = {0.f,0.f,0.f,0.f}, acc1 = {0.f,0.f,0.f,0.f};
    f32x4 acc2 = {0.f,0.f,0.f,0.f}, acc3 = {0.f,0.f,0.f,0.f};
    #pragma unroll
    for (int ks = 0; ks < 4; ++ks) {
      const int frag = hblk * 4 + ks;
      const short8v bfr = *(const short8v*)(Bp + ((size_t)frag << 9) + (lane << 3));
      acc0 = __builtin_amdgcn_mfma_f32_16x16x32_bf16(afr[0][ks], bfr, acc0, 0, 0, 0);
      acc1 = __builtin_amdgcn_mfma_f32_16x16x32_bf16(afr[1][ks], bfr, acc1, 0, 0, 0);
      acc2 = __builtin_amdgcn_mfma_f32_16x16x32_bf16(afr[2][ks], bfr, acc2, 0, 0, 0);
      acc3 = __builtin_amdgcn_mfma_f32_16x16x32_bf16(afr[3][ks], bfr, acc3, 0, 0, 0);
    }
    const float zv = zb1s[hrow], wgt = w2s[hrow];
    #pragma unroll
    for (int j = 0; j < 4; ++j) {
      fsum[0][j] += fmaxf(acc0[j] + zv, 0.f) * wgt;
      fsum[1][j] += fmaxf(acc1[j] + zv, 0.f) * wgt;
      fsum[2][j] += fmaxf(acc2[j] + zv, 0.f) * wgt;
      fsum[3][j] += fmaxf(acc3[j] + zv, 0.f) * wgt;
    }
  }
  // reduce over 16 h-columns (lane bits 0..3)
  #pragma unroll
  for (int m = 0; m < 4; ++m)
    #pragma unroll
    for (int j = 0; j < 4; ++j) {
      float v = fsum[m][j];
      v += __shfl_xor(v, 1); v += __shfl_xor(v, 2);
      v += __shfl_xor(v, 4); v += __shfl_xor(v, 8);
      fsum[m][j] = v;
    }
  if (hl == 0) {
    const int rb = (lane >> 4) * 4;
    #pragma unroll
    for (int m = 0; m < 4; ++m)
      #pragma unroll
      for (int j = 0; j < 4; ++j)
        red[wv][m * 16 + rb + j] = fsum[m][j];
  }
  __syncthreads();

  // partial logsumexp over this block's 64 f values
  if (t < 64) {
    const float fval = red[0][t] + red[1][t] + red[2][t] + red[3][t] + b2[0];
    float mm = fval;
    #pragma unroll
    for (int o = 1; o < 64; o <<= 1) mm = fmaxf(mm, __shfl_xor(mm, o));
    float e = expf(fval - mm);
    #pragma unroll
    for (int o = 1; o < 64; o <<= 1) e += __shfl_xor(e, o);
    if (t == 0) { mpart[blk] = mm; lpart[blk] = e; }
  }
}

// ============ finisher: 128 blocks x 128 thr ============
__global__ __launch_bounds__(128) void Kfin(
    const float* __restrict__ mpart, const float* __restrict__ lpart,
    const float* __restrict__ l2part, const float* __restrict__ bvec,
    const float* __restrict__ w, const float* __restrict__ pxw_part,
    const float* __restrict__ fzw_part, const float* __restrict__ b2,
    float* __restrict__ out) {
  const int b = blockIdx.x, t = threadIdx.x;
  __shared__ float red3[2];
  const int lane = t & 63, wid = t >> 6;
  // pwx finish
  float lg = bvec[t];
  #pragma unroll
  for (int kc = 0; kc < 8; ++kc) lg += l2part[((size_t)b * 8 + kc) * 128 + t];
  float term = w[b * 128 + t] * lg - softplusf(lg);
  #pragma unroll
  for (int o = 1; o < 64; o <<= 1) term += __shfl_xor(term, o);
  if (lane == 0) red3[wid] = term;
  __syncthreads();
  if (t == 0) {
    const float pwx = red3[0] + red3[1];
    // combine 4 logsumexp partials
    const float m0 = mpart[b], m1 = mpart[128 + b],
                m2 = mpart[256 + b], m3 = mpart[384 + b];
    const float mm = fmaxf(fmaxf(m0, m1), fmaxf(m2, m3));
    const float l = lpart[b] * expf(m0 - mm) + lpart[128 + b] * expf(m1 - mm)
                  + lpart[256 + b] * expf(m2 - mm) + lpart[384 + b] * expf(m3 - mm);
    const float logZ = mm + logf(l) - logf((float)S_) + (float)D_ * logf(2.f);
    float pxw = 0.f;
    #pragma unroll
    for (int ic = 0; ic < 8; ++ic) pxw += pxw_part[b * 8 + ic];
    const float fzw = fzw_part[b * 8 + 0] + fzw_part[b * 8 + 1] + fzw_part[b * 8 + 2]
                    + fzw_part[b * 8 + 3] + fzw_part[b * 8 + 4] + fzw_part[b * 8 + 5]
                    + fzw_part[b * 8 + 6] + fzw_part[b * 8 + 7] + b2[0];
    const float r_wz = fminf(fzw - logZ, 0.f);
    out[b] = -(pxw - pwx + r_wz);
  }
}

extern "C" void kernel_launch(void* const* d_in, const int* in_sizes, int n_in,
                              void* d_out, int out_size, void* d_ws, size_t ws_size,
                              hipStream_t stream) {
  const float* x    = (const float*)d_in[0];
  // d_in[1] = y, unused
  const float* w    = (const float*)d_in[2];
  const float* z    = (const float*)d_in[3];
  const float* wt   = (const float*)d_in[4];
  const float* W    = (const float*)d_in[5];
  const float* bvec = (const float*)d_in[6];
  const float* cvec = (const float*)d_in[7];
  const float* W1   = (const float*)d_in[8];
  const float* b1   = (const float*)d_in[9];
  const float* W2   = (const float*)d_in[10];
  const float* b2   = (const float*)d_in[11];

  float* ws_f = (float*)d_ws;
  float* zb1            = ws_f;                              // 65536 f
  unsigned short* Bp    = (unsigned short*)(ws_f + 65536);   // 65536 us (32768 f)
  float* l2part         = ws_f + 98304;                      // 131072 f
  float* pxw_part       = ws_f + 229376;                     // 1024 f
  float* fzw_part       = ws_f + 230400;                     // 1024 f
  float* mpart          = ws_f + 231424;                     // 512 f
  float* lpart          = ws_f + 231936;                     // 512 f
  float* out = (float*)d_out;

  hipLaunchKernelGGL(Kprep, dim3(704), dim3(256), 0, stream,
                     x, w, z, W, cvec, W1, b1, W2, Bp, l2part, pxw_part, zb1, fzw_part);
  hipLaunchKernelGGL(Kmfma, dim3(512), dim3(256), 0, stream,
                     wt, Bp, zb1, W2, b2, mpart, lpart);
  hipLaunchKernelGGL(Kfin, dim3(B_), dim3(128), 0, stream,
                     mpart, lpart, l2part, bvec, w, pxw_part, fzw_part, b2, out);
}

// Round 9
// 36.787 us; speedup vs baseline: 1.1912x; 1.1912x over previous
//
#include <hip/hip_runtime.h>
#include <hip/hip_bf16.h>
#include <math.h>

#define B_ 128
#define IN_ 1024
#define D_ 128
#define H_ 512
#define S_ 256

typedef __attribute__((ext_vector_type(8))) short short8v;
typedef __attribute__((ext_vector_type(8))) unsigned short ushort8v;
typedef __attribute__((ext_vector_type(4))) unsigned short ushort4v;
typedef __attribute__((ext_vector_type(4))) float f32x4;

__device__ __forceinline__ float softplusf(float x) {
  return fmaxf(x, 0.f) + log1pf(expf(-fabsf(x)));
}

__device__ __forceinline__ unsigned short f2bf(float f) {
  unsigned u = __float_as_uint(f);
  unsigned r = (u + 0x7fff + ((u >> 16) & 1)) >> 16;   // RNE
  return (unsigned short)r;
}

// ============ fused prep kernel (round-5 best-measured version) ============
// [0,64)      : pack W1 w-half -> bf16 MFMA-fragment order Bp
// [64,1088)   : log_pwx partial logits  (b x kc-of-8, 128 i-rows each)
// [1088,1600) : log_pxw partials        (b x ic-of-4) — 16-lane/row coalesced
// [1600,1856) : zb1 + f_zw partials     (b-quad x hc-of-8) — 16-lane/row coalesced
__global__ __launch_bounds__(256) void Kprep(
    const float* __restrict__ x, const float* __restrict__ w,
    const float* __restrict__ z, const float* __restrict__ W,
    const float* __restrict__ cvec, const float* __restrict__ W1,
    const float* __restrict__ b1, const float* __restrict__ W2,
    unsigned short* __restrict__ Bp, float* __restrict__ l2part,
    float* __restrict__ pxw_part, float* __restrict__ zb1,
    float* __restrict__ fzw_part) {
  __shared__ float smem[1024];
  const int blk = blockIdx.x;
  const int t = threadIdx.x;

  if (blk < 64) {
    // ---- pack Bp (verified): frag=hblk*4+ks, h=hblk*16+(l&15), k=ks*32+(l>>4)*8+j
    const int o = (blk * 256 + t) * 4;
    const int frag = o >> 9;
    const int l = (o >> 3) & 63;
    const int j0 = o & 7;
    const int h = (frag >> 2) * 16 + (l & 15);
    const int k0 = (frag & 3) * 32 + ((l >> 4) << 3) + j0;
    const float4 v = *(const float4*)(W1 + (size_t)h * 256 + 128 + k0);
    ushort4v u;
    u[0] = f2bf(v.x); u[1] = f2bf(v.y); u[2] = f2bf(v.z); u[3] = f2bf(v.w);
    *(ushort4v*)(Bp + o) = u;
  } else if (blk < 1088) {
    // ---- pwx partial: (b, kc of 8): 128 i-rows
    const int bb = blk - 64;
    const int b = bb >> 3, kc = bb & 7;
    float* xs = smem;            // 128
    float* p2 = smem + 128;      // 256
    if (t < 128) xs[t] = x[b * IN_ + kc * 128 + t];
    __syncthreads();
    const int d = t & 127, ks = t >> 7;
    const float* __restrict__ Wp = W + (size_t)(kc * 128 + ks * 64) * D_ + d;
    float s = 0.f;
    #pragma unroll 8
    for (int i = 0; i < 64; ++i) s = fmaf(xs[ks * 64 + i], Wp[(size_t)i * D_], s);
    p2[ks * 128 + d] = s;
    __syncthreads();
    if (t < 128) l2part[((size_t)b * 8 + kc) * 128 + t] = p2[t] + p2[128 + t];
  } else if (blk < 1600) {
    // ---- pxw partial: (b, ic of 4), 16 lanes per i-row
    const int bb = blk - 1088;
    const int b = bb >> 2, ic = bb & 3;
    float* ws_ = smem;           // 128
    float* red = smem + 128;     // 4
    if (t < 128) ws_[t] = w[b * 128 + t];
    __syncthreads();
    const int chunk = t & 15, rgrp = t >> 4;
    float wreg[8];
    #pragma unroll
    for (int j = 0; j < 8; ++j) wreg[j] = ws_[chunk * 8 + j];
    float term = 0.f;
    #pragma unroll 2
    for (int it = 0; it < 16; ++it) {
      const int i = ic * 256 + it * 16 + rgrp;
      const float4* __restrict__ rp = (const float4*)(W + (size_t)i * D_ + chunk * 8);
      const float4 va = rp[0], vb = rp[1];
      float dot = 0.f;
      dot = fmaf(va.x, wreg[0], dot); dot = fmaf(va.y, wreg[1], dot);
      dot = fmaf(va.z, wreg[2], dot); dot = fmaf(va.w, wreg[3], dot);
      dot = fmaf(vb.x, wreg[4], dot); dot = fmaf(vb.y, wreg[5], dot);
      dot = fmaf(vb.z, wreg[6], dot); dot = fmaf(vb.w, wreg[7], dot);
      dot += __shfl_xor(dot, 1); dot += __shfl_xor(dot, 2);
      dot += __shfl_xor(dot, 4); dot += __shfl_xor(dot, 8);
      if (chunk == 0) {
        const float lg = dot + cvec[i];
        term += x[b * IN_ + i] * lg - softplusf(lg);
      }
    }
    #pragma unroll
    for (int o = 32; o > 0; o >>= 1) term += __shfl_down(term, o);
    const int lane = t & 63, wid = t >> 6;
    if (lane == 0) red[wid] = term;
    __syncthreads();
    if (t == 0) pxw_part[b * 4 + ic] = red[0] + red[1] + red[2] + red[3];
  } else {
    // ---- zw: (b-quad, hc of 8), wave = b, 16 lanes per h-row
    const int bb = blk - 1600;
    const int bq = bb >> 3, hc = bb & 7;
    float* zs  = smem;           // 512
    float* ws2 = smem + 512;     // 512
    for (int e = t; e < 512; e += 256) {
      zs[e]  = z[bq * 512 + e];
      ws2[e] = w[bq * 512 + e];
    }
    __syncthreads();
    const int bs = t >> 6, lane = t & 63;
    const int c16 = lane & 15, rsub = lane >> 4;
    const int b = bq * 4 + bs;
    float zreg[16];
    #pragma unroll
    for (int j = 0; j < 16; ++j)
      zreg[j] = (c16 < 8) ? zs[bs * 128 + c16 * 16 + j]
                          : ws2[bs * 128 + c16 * 16 - 128 + j];
    float fpacc = 0.f;
    #pragma unroll 2
    for (int it = 0; it < 16; ++it) {
      const int h = hc * 64 + it * 4 + rsub;
      const float4* __restrict__ rp = (const float4*)(W1 + (size_t)h * 256 + c16 * 16);
      float dot = 0.f;
      #pragma unroll
      for (int q = 0; q < 4; ++q) {
        const float4 v = rp[q];
        dot = fmaf(v.x, zreg[4 * q + 0], dot);
        dot = fmaf(v.y, zreg[4 * q + 1], dot);
        dot = fmaf(v.z, zreg[4 * q + 2], dot);
        dot = fmaf(v.w, zreg[4 * q + 3], dot);
      }
      dot += __shfl_xor(dot, 1); dot += __shfl_xor(dot, 2);
      dot += __shfl_xor(dot, 4);
      const float other = __shfl_xor(dot, 8);
      if (c16 == 0) {
        const float zp = dot + b1[h];
        zb1[(size_t)b * H_ + h] = zp;
        fpacc += fmaxf(zp + other, 0.f) * W2[h];
      }
    }
    fpacc += __shfl_xor(fpacc, 16);
    fpacc += __shfl_xor(fpacc, 32);
    if (lane == 0) fzw_part[b * 8 + hc] = fpacc;
  }
}

// ============ main fused kernel: one block per b (round-5 best-measured) ============
__global__ __launch_bounds__(1024) void Kmain(
    const float* __restrict__ wt, const unsigned short* __restrict__ Bp,
    const float* __restrict__ zb1, const float* __restrict__ W2,
    const float* __restrict__ b2, const float* __restrict__ l2part,
    const float* __restrict__ bvec, const float* __restrict__ w,
    const float* __restrict__ pxw_part, const float* __restrict__ fzw_part,
    float* __restrict__ out) {
  const int b = blockIdx.x;
  const int t = threadIdx.x;
  const int lane = t & 63, wvid = t >> 6;      // wave 0..15
  const int sc = wvid >> 2, nh = (wvid >> 1) & 1, nth = wvid & 1;

  __shared__ unsigned short atile[256 * 128];  // 64 KB, XOR-swizzled bf16
  __shared__ float zb1s[H_];
  __shared__ float w2s[H_];
  __shared__ float red[16][64];
  __shared__ float mred[4], ered[4], pred[2], miscs[2];

  if (t < 512) { zb1s[t] = zb1[(size_t)b * H_ + t]; w2s[t] = W2[t]; }

  // stage A: 256 rows x 128 d, fp32 -> bf16, granule swizzle g ^= r&15
  {
    const int r = t >> 2;
    const int g0 = (t & 3) * 4;
    const float* __restrict__ src = wt + ((size_t)r * B_ + b) * D_;
    #pragma unroll
    for (int gg = 0; gg < 4; ++gg) {
      const int g = g0 + gg;
      const float4 v0 = *(const float4*)(src + g * 8);
      const float4 v1 = *(const float4*)(src + g * 8 + 4);
      ushort8v u;
      u[0] = f2bf(v0.x); u[1] = f2bf(v0.y); u[2] = f2bf(v0.z); u[3] = f2bf(v0.w);
      u[4] = f2bf(v1.x); u[5] = f2bf(v1.y); u[6] = f2bf(v1.z); u[7] = f2bf(v1.w);
      *(ushort8v*)&atile[r * 128 + ((g ^ (r & 15)) << 3)] = u;
    }
  }
  __syncthreads();

  short8v afr[4][4];
  #pragma unroll
  for (int m = 0; m < 4; ++m) {
    const int arow = sc * 64 + m * 16 + (lane & 15);
    #pragma unroll
    for (int ks = 0; ks < 4; ++ks) {
      const int g = ks * 4 + (lane >> 4);
      afr[m][ks] = *(const short8v*)&atile[arow * 128 + ((g ^ (arow & 15)) << 3)];
    }
  }

  float fsum[4][4];
  #pragma unroll
  for (int m = 0; m < 4; ++m)
    #pragma unroll
    for (int j = 0; j < 4; ++j) fsum[m][j] = 0.f;

  const int hl = lane & 15;
  #pragma unroll 2
  for (int nt = 0; nt < 8; ++nt) {
    const int hblk = nh * 16 + nth * 8 + nt;
    const int hrow = hblk * 16 + hl;
    f32x4 acc0 = {0.f,0.f,0.f,0.f}, acc1 = {0.f,0.f,0.f,0.f};
    f32x4 acc2 = {0.f,0.f,0.f,0.f}, acc3 = {0.f,0.f,0.f,0.f};
    #pragma unroll
    for (int ks = 0; ks < 4; ++ks) {
      const int frag = hblk * 4 + ks;
      const short8v bfr = *(const short8v*)(Bp + ((size_t)frag << 9) + (lane << 3));
      acc0 = __builtin_amdgcn_mfma_f32_16x16x32_bf16(afr[0][ks], bfr, acc0, 0, 0, 0);
      acc1 = __builtin_amdgcn_mfma_f32_16x16x32_bf16(afr[1][ks], bfr, acc1, 0, 0, 0);
      acc2 = __builtin_amdgcn_mfma_f32_16x16x32_bf16(afr[2][ks], bfr, acc2, 0, 0, 0);
      acc3 = __builtin_amdgcn_mfma_f32_16x16x32_bf16(afr[3][ks], bfr, acc3, 0, 0, 0);
    }
    const float zv = zb1s[hrow], wgt = w2s[hrow];
    #pragma unroll
    for (int j = 0; j < 4; ++j) {
      fsum[0][j] += fmaxf(acc0[j] + zv, 0.f) * wgt;
      fsum[1][j] += fmaxf(acc1[j] + zv, 0.f) * wgt;
      fsum[2][j] += fmaxf(acc2[j] + zv, 0.f) * wgt;
      fsum[3][j] += fmaxf(acc3[j] + zv, 0.f) * wgt;
    }
  }
  #pragma unroll
  for (int m = 0; m < 4; ++m)
    #pragma unroll
    for (int j = 0; j < 4; ++j) {
      float v = fsum[m][j];
      v += __shfl_xor(v, 1); v += __shfl_xor(v, 2);
      v += __shfl_xor(v, 4); v += __shfl_xor(v, 8);
      fsum[m][j] = v;
    }
  if (hl == 0) {
    const int rb = (lane >> 4) * 4;
    #pragma unroll
    for (int m = 0; m < 4; ++m)
      #pragma unroll
      for (int j = 0; j < 4; ++j)
        red[wvid][m * 16 + rb + j] = fsum[m][j];
  }
  __syncthreads();

  // ---- fused finisher ----
  float fval = 0.f;
  if (t < 256) {
    const int sc2 = t >> 6, r = t & 63;
    fval = red[sc2 * 4 + 0][r] + red[sc2 * 4 + 1][r]
         + red[sc2 * 4 + 2][r] + red[sc2 * 4 + 3][r] + b2[0];
    float mm = fval;
    #pragma unroll
    for (int o = 1; o < 64; o <<= 1) mm = fmaxf(mm, __shfl_xor(mm, o));
    if (lane == 0) mred[wvid] = mm;
  } else if (t < 384) {
    const int d = t - 256;
    float lg = bvec[d];
    #pragma unroll
    for (int kc = 0; kc < 8; ++kc) lg += l2part[((size_t)b * 8 + kc) * 128 + d];
    float term = w[b * 128 + d] * lg - softplusf(lg);
    #pragma unroll
    for (int o = 1; o < 64; o <<= 1) term += __shfl_xor(term, o);
    if (lane == 0) pred[wvid - 4] = term;
  } else if (t == 384) {
    miscs[0] = pxw_part[b * 4] + pxw_part[b * 4 + 1]
             + pxw_part[b * 4 + 2] + pxw_part[b * 4 + 3];
  } else if (t == 385) {
    miscs[1] = fzw_part[b * 8 + 0] + fzw_part[b * 8 + 1] + fzw_part[b * 8 + 2]
             + fzw_part[b * 8 + 3] + fzw_part[b * 8 + 4] + fzw_part[b * 8 + 5]
             + fzw_part[b * 8 + 6] + fzw_part[b * 8 + 7];
  }
  __syncthreads();
  if (t < 256) {
    const float mm = fmaxf(fmaxf(mred[0], mred[1]), fmaxf(mred[2], mred[3]));
    float e = expf(fval - mm);
    #pragma unroll
    for (int o = 1; o < 64; o <<= 1) e += __shfl_xor(e, o);
    if (lane == 0) ered[wvid] = e;
  }
  __syncthreads();
  if (t == 0) {
    const float mm = fmaxf(fmaxf(mred[0], mred[1]), fmaxf(mred[2], mred[3]));
    const float tot = ered[0] + ered[1] + ered[2] + ered[3];
    const float logZ = mm + logf(tot) - logf((float)S_) + (float)D_ * logf(2.f);
    const float pwx = pred[0] + pred[1];
    const float pxw = miscs[0];
    const float fzw = miscs[1] + b2[0];
    const float r_wz = fminf(fzw - logZ, 0.f);
    out[b] = -(pxw - pwx + r_wz);
  }
}

extern "C" void kernel_launch(void* const* d_in, const int* in_sizes, int n_in,
                              void* d_out, int out_size, void* d_ws, size_t ws_size,
                              hipStream_t stream) {
  const float* x    = (const float*)d_in[0];
  // d_in[1] = y, unused
  const float* w    = (const float*)d_in[2];
  const float* z    = (const float*)d_in[3];
  const float* wt   = (const float*)d_in[4];
  const float* W    = (const float*)d_in[5];
  const float* bvec = (const float*)d_in[6];
  const float* cvec = (const float*)d_in[7];
  const float* W1   = (const float*)d_in[8];
  const float* b1   = (const float*)d_in[9];
  const float* W2   = (const float*)d_in[10];
  const float* b2   = (const float*)d_in[11];

  float* ws_f = (float*)d_ws;
  float* zb1            = ws_f;                              // 65536 f
  unsigned short* Bp    = (unsigned short*)(ws_f + 65536);   // 65536 us (32768 f)
  float* l2part         = ws_f + 98304;                      // 131072 f
  float* pxw_part       = ws_f + 229376;                     // 512 f
  float* fzw_part       = ws_f + 229888;                     // 1024 f
  float* out = (float*)d_out;

  hipLaunchKernelGGL(Kprep, dim3(1856), dim3(256), 0, stream,
                     x, w, z, W, cvec, W1, b1, W2, Bp, l2part, pxw_part, zb1, fzw_part);
  hipLaunchKernelGGL(Kmain, dim3(B_), dim3(1024), 0, stream,
                     wt, Bp, zb1, W2, b2, l2part, bvec, w, pxw_part, fzw_part, out);
}